// Round 7
// baseline (487.849 us; speedup 1.0000x reference)
//
#include <hip/hip_runtime.h>
#include <hip/hip_bf16.h>
#include <hip/hip_fp16.h>
#include <cstdint>

#define IN_DIM 128
#define OUT_DIM 64
#define FEATD 50
#define NEG_SLOPE 0.01f

typedef unsigned int uint32;
typedef _Float16 half4 __attribute__((ext_vector_type(4)));
typedef float f32x4 __attribute__((ext_vector_type(4)));

// K0: v3[j] = sum_o W_attn[128+o] * W_feat[o*FEATD+j]  (block 0) + zero cnt
__global__ __launch_bounds__(256) void k_v3zero(const float* __restrict__ W_feat,
                                                const float* __restrict__ W_attn,
                                                float* __restrict__ v3,
                                                uint32* __restrict__ cnt,
                                                int n_sents) {
  int i = blockIdx.x * 256 + threadIdx.x;
  if (i < n_sents) cnt[i] = 0u;
  if (blockIdx.x == 0 && threadIdx.x < FEATD) {
    int j = threadIdx.x;
    float s = 0.f;
    #pragma unroll
    for (int o = 0; o < OUT_DIM; ++o)
      s = fmaf(W_attn[2 * OUT_DIM + o], W_feat[o * FEATD + j], s);
    v3[j] = s;
  }
}

// K1: node GEMM on matrix cores (round-5 version, standalone).
__global__ __launch_bounds__(256) void k_node_mfma(const float* __restrict__ h,
    const float* __restrict__ W_fc, const float* __restrict__ W_attn,
    __half* __restrict__ z, float* __restrict__ s1, float* __restrict__ s2,
    int n_words, int n_nodes) {
  __shared__ float zl[4][16][68];  // +4 pad: conflict-free transpose
  int w = threadIdx.x >> 6, lane = threadIdx.x & 63;
  int nb = blockIdx.x * 64 + w * 16;
  int lrow = lane & 15;
  int lk4 = (lane >> 4) * 4;

  int an = nb + lrow;
  if (an >= n_nodes) an = n_nodes - 1;  // clamp; stores guarded later
  const float* hrow = h + (size_t)an * IN_DIM;

  f32x4 acc[4];
  #pragma unroll
  for (int nt = 0; nt < 4; ++nt) acc[nt] = (f32x4){0.f, 0.f, 0.f, 0.f};

  #pragma unroll
  for (int ks = 0; ks < 8; ++ks) {
    float4 hv = *(const float4*)(hrow + ks * 16 + lk4);
    half4 a;
    a[0] = (_Float16)hv.x; a[1] = (_Float16)hv.y;
    a[2] = (_Float16)hv.z; a[3] = (_Float16)hv.w;
    #pragma unroll
    for (int nt = 0; nt < 4; ++nt) {
      const float* wrow = W_fc + (size_t)(nt * 16 + lrow) * IN_DIM + ks * 16 + lk4;
      float4 wv = *(const float4*)wrow;
      half4 b;
      b[0] = (_Float16)wv.x; b[1] = (_Float16)wv.y;
      b[2] = (_Float16)wv.z; b[3] = (_Float16)wv.w;
      acc[nt] = __builtin_amdgcn_mfma_f32_16x16x16f16(a, b, acc[nt], 0, 0, 0);
    }
  }

  int drow = (lane >> 4) * 4;
  #pragma unroll
  for (int nt = 0; nt < 4; ++nt)
    #pragma unroll
    for (int r = 0; r < 4; ++r)
      zl[w][drow + r][nt * 16 + lrow] = acc[nt][r];

  int node = lane >> 2;    // 0..15
  int chunk = lane & 3;    // 0..3, 16 outs each
  float v[16];
  #pragma unroll
  for (int q = 0; q < 4; ++q) {
    float4 t = *(const float4*)&zl[w][node][chunk * 16 + q * 4];
    v[4 * q + 0] = t.x; v[4 * q + 1] = t.y;
    v[4 * q + 2] = t.z; v[4 * q + 3] = t.w;
  }

  int gn = nb + node;
  bool valid = gn < n_nodes;
  bool isword = gn < n_words;
  const float* wa = W_attn + (isword ? 0 : OUT_DIM) + chunk * 16;
  float p = 0.f;
  #pragma unroll
  for (int t = 0; t < 16; ++t) p = fmaf(v[t], wa[t], p);
  p += __shfl_xor(p, 1);
  p += __shfl_xor(p, 2);

  if (valid && chunk == 0) {
    if (isword) s1[gn] = p; else s2[gn - n_words] = p;
  }
  if (valid && isword) {
    uint32 d[8];
    #pragma unroll
    for (int k = 0; k < 8; ++k) {
      __half2 t = __floats2half2_rn(v[2 * k], v[2 * k + 1]);
      d[k] = *(uint32*)&t;
    }
    uint4* dstp = (uint4*)(z + (size_t)gn * OUT_DIM + chunk * 16);
    dstp[0] = make_uint4(d[0], d[1], d[2], d[3]);
    dstp[1] = make_uint4(d[4], d[5], d[6], d[7]);
  }
}

// K2: histogram of dst + per-edge rank (round-5 version)
__global__ __launch_bounds__(256) void k_hist(const int* __restrict__ dst,
                                              uint32* __restrict__ cnt,
                                              uint32* __restrict__ rank, int E) {
  int e = blockIdx.x * 256 + threadIdx.x;
  if (e < E) rank[e] = atomicAdd(&cnt[dst[e]], 1u);
}

// K3: exclusive scan of cnt[0..n) -> off[0..n]
__global__ __launch_bounds__(1024) void k_scan(const uint32* __restrict__ cnt,
    uint32* __restrict__ off, int n) {
  __shared__ uint32 part[1024];
  int t = threadIdx.x;
  int CH = (n + 1023) >> 10;
  int base = t * CH;
  uint32 s = 0;
  for (int k = 0; k < CH; ++k) { int i = base + k; if (i < n) s += cnt[i]; }
  part[t] = s;
  __syncthreads();
  uint32 x = s;
  for (int d = 1; d < 1024; d <<= 1) {
    uint32 v = (t >= d) ? part[t - d] : 0u;
    __syncthreads();
    x += v;
    part[t] = x;
    __syncthreads();
  }
  uint32 run = (t > 0) ? part[t - 1] : 0u;
  for (int k = 0; k < CH; ++k) {
    int i = base + k;
    if (i < n) { off[i] = run; run += cnt[i]; }
  }
  if (t == 1023) off[n] = part[1023];
}

// K4: TWO edges per thread. A row-pair is 400 B = exactly 25 aligned float4
// loads (400*t is 16B-aligned); halves VMEM instruction count per edge and
// keeps every lane active in the gather/exp/scatter epilogue.
__global__ __launch_bounds__(256) void k_edge(const float* __restrict__ tfidf,
    const int* __restrict__ src, const int* __restrict__ dst,
    const float* __restrict__ s1, const float* __restrict__ s2,
    const float* __restrict__ v3, const uint32* __restrict__ off,
    const uint32* __restrict__ rank, float2* __restrict__ pair, int E) {
  int t = blockIdx.x * 256 + threadIdx.x;
  int e0 = t * 2;
  if (e0 >= E) return;
  const float4* row4 = (const float4*)(tfidf + (size_t)e0 * FEATD);
  float f0 = 0.f, f1 = 0.f;
  #pragma unroll
  for (int q = 0; q < 12; ++q) {          // edge0: floats 0..47
    float4 v = row4[q];
    f0 = fmaf(v.x, v3[4 * q + 0], f0);
    f0 = fmaf(v.y, v3[4 * q + 1], f0);
    f0 = fmaf(v.z, v3[4 * q + 2], f0);
    f0 = fmaf(v.w, v3[4 * q + 3], f0);
  }
  {                                        // split quad: 48,49 | 50,51
    float4 v = row4[12];
    f0 = fmaf(v.x, v3[48], f0);
    f0 = fmaf(v.y, v3[49], f0);
    f1 = fmaf(v.z, v3[0], f1);
    f1 = fmaf(v.w, v3[1], f1);
  }
  #pragma unroll
  for (int q = 13; q < 25; ++q) {         // edge1: floats 52..99 -> v3[2..49]
    float4 v = row4[q];
    f1 = fmaf(v.x, v3[4 * q - 50], f1);
    f1 = fmaf(v.y, v3[4 * q - 49], f1);
    f1 = fmaf(v.z, v3[4 * q - 48], f1);
    f1 = fmaf(v.w, v3[4 * q - 47], f1);
  }

  int2 sp = *(const int2*)(src + e0);
  int2 dp = *(const int2*)(dst + e0);
  uint2 rp = *(const uint2*)(rank + e0);

  float ev0 = s1[sp.x] + s2[dp.x] + f0;
  ev0 = ev0 >= 0.f ? ev0 : NEG_SLOPE * ev0;
  float2 pr0;
  pr0.x = __expf(ev0);
  pr0.y = __int_as_float(sp.x);
  pair[off[dp.x] + rp.x] = pr0;

  if (e0 + 1 < E) {
    float ev1 = s1[sp.y] + s2[dp.y] + f1;
    ev1 = ev1 >= 0.f ? ev1 : NEG_SLOPE * ev1;
    float2 pr1;
    pr1.x = __expf(ev1);
    pr1.y = __int_as_float(sp.y);
    pair[off[dp.y] + rp.y] = pr1;
  }
}

// K5: one wave per sentence (4 per block), no cross-wave reduction.
__global__ __launch_bounds__(256) void k_agg(const __half* __restrict__ z,
    const float2* __restrict__ pair, const uint32* __restrict__ off,
    float* __restrict__ out, int n_sents) {
  int w = threadIdx.x >> 6, lane = threadIdx.x & 63;
  int s = blockIdx.x * 4 + w;
  if (s >= n_sents) return;
  uint32 j0 = off[s], j1 = off[s + 1];

  float acc = 0.f, sa = 0.f;
  uint32 j = j0;
  for (; j + 8 <= j1; j += 8) {
    float2 p[8];
    #pragma unroll
    for (int k = 0; k < 8; ++k) p[k] = pair[j + k];
    float v[8];
    #pragma unroll
    for (int k = 0; k < 8; ++k)
      v[k] = __half2float(z[(size_t)(uint32)__float_as_int(p[k].y) * OUT_DIM + lane]);
    #pragma unroll
    for (int k = 0; k < 8; ++k) { acc = fmaf(p[k].x, v[k], acc); sa += p[k].x; }
  }
  for (; j + 4 <= j1; j += 4) {
    float2 p[4];
    #pragma unroll
    for (int k = 0; k < 4; ++k) p[k] = pair[j + k];
    float v[4];
    #pragma unroll
    for (int k = 0; k < 4; ++k)
      v[k] = __half2float(z[(size_t)(uint32)__float_as_int(p[k].y) * OUT_DIM + lane]);
    #pragma unroll
    for (int k = 0; k < 4; ++k) { acc = fmaf(p[k].x, v[k], acc); sa += p[k].x; }
  }
  for (; j < j1; ++j) {
    float2 p = pair[j];
    float v = __half2float(z[(size_t)(uint32)__float_as_int(p.y) * OUT_DIM + lane]);
    acc = fmaf(p.x, v, acc);
    sa += p.x;
  }

  out[(size_t)s * OUT_DIM + lane] = (sa > 0.f) ? (acc / sa) : 0.f;
}

extern "C" void kernel_launch(void* const* d_in, const int* in_sizes, int n_in,
                              void* d_out, int out_size, void* d_ws, size_t ws_size,
                              hipStream_t stream) {
  const float* h      = (const float*)d_in[0];
  const float* tfidf  = (const float*)d_in[1];
  const float* W_fc   = (const float*)d_in[2];
  const float* W_feat = (const float*)d_in[3];
  const float* W_attn = (const float*)d_in[4];
  const int*   src    = (const int*)d_in[5];
  const int*   dst    = (const int*)d_in[6];

  int n_nodes = in_sizes[0] / IN_DIM;   // 220000
  int E       = in_sizes[5];            // 2,000,000
  int n_sents = out_size / OUT_DIM;     // 20000
  int n_words = n_nodes - n_sents;      // 200000
  float* out = (float*)d_out;

  char* ws = (char*)d_ws;
  size_t ofs = 0;
  auto alloc = [&](size_t bytes) -> char* {
    char* p = ws + ofs;
    ofs += (bytes + 255) / 256 * 256;
    return p;
  };
  __half* z      = (__half*)alloc((size_t)n_words * OUT_DIM * 2);
  float*  s1     = (float*)alloc((size_t)n_words * 4);
  float*  s2     = (float*)alloc((size_t)n_sents * 4);
  float2* pair   = (float2*)alloc((size_t)E * 8);
  uint32* rank   = (uint32*)alloc((size_t)E * 4);
  uint32* cnt    = (uint32*)alloc((size_t)n_sents * 4);
  uint32* offs   = (uint32*)alloc((size_t)(n_sents + 1) * 4);
  float*  v3     = (float*)alloc(FEATD * 4);
  (void)ws_size; (void)n_in;

  k_v3zero<<<(n_sents + 255) / 256, 256, 0, stream>>>(W_feat, W_attn, v3, cnt,
                                                      n_sents);
  k_node_mfma<<<(n_nodes + 63) / 64, 256, 0, stream>>>(h, W_fc, W_attn, z, s1,
                                                       s2, n_words, n_nodes);
  k_hist<<<(E + 255) / 256, 256, 0, stream>>>(dst, cnt, rank, E);
  k_scan<<<1, 1024, 0, stream>>>(cnt, offs, n_sents);
  k_edge<<<(E / 2 + 255) / 256, 256, 0, stream>>>(tfidf, src, dst, s1, s2, v3,
                                                  offs, rank, pair, E);
  k_agg<<<(n_sents + 3) / 4, 256, 0, stream>>>(z, pair, offs, out, n_sents);
}

// Round 8
// 430.556 us; speedup vs baseline: 1.1331x; 1.1331x over previous
//
#include <hip/hip_runtime.h>
#include <hip/hip_bf16.h>
#include <hip/hip_fp16.h>
#include <cstdint>

#define IN_DIM 128
#define OUT_DIM 64
#define FEATD 50
#define FPAD 51
#define NEG_SLOPE 0.01f

typedef unsigned int uint32;
typedef _Float16 half4 __attribute__((ext_vector_type(4)));
typedef float f32x4 __attribute__((ext_vector_type(4)));

// K0: v3[j] = sum_o W_attn[128+o] * W_feat[o*FEATD+j]  (block 0) + zero cnt
__global__ __launch_bounds__(256) void k_v3zero(const float* __restrict__ W_feat,
                                                const float* __restrict__ W_attn,
                                                float* __restrict__ v3,
                                                uint32* __restrict__ cnt,
                                                int n_sents) {
  int i = blockIdx.x * 256 + threadIdx.x;
  if (i < n_sents) cnt[i] = 0u;
  if (blockIdx.x == 0 && threadIdx.x < FEATD) {
    int j = threadIdx.x;
    float s = 0.f;
    #pragma unroll
    for (int o = 0; o < OUT_DIM; ++o)
      s = fmaf(W_attn[2 * OUT_DIM + o], W_feat[o * FEATD + j], s);
    v3[j] = s;
  }
}

// K1: node GEMM on matrix cores (round-5 version, frozen).
__global__ __launch_bounds__(256) void k_node_mfma(const float* __restrict__ h,
    const float* __restrict__ W_fc, const float* __restrict__ W_attn,
    __half* __restrict__ z, float* __restrict__ s1, float* __restrict__ s2,
    int n_words, int n_nodes) {
  __shared__ float zl[4][16][68];  // +4 pad: conflict-free transpose
  int w = threadIdx.x >> 6, lane = threadIdx.x & 63;
  int nb = blockIdx.x * 64 + w * 16;
  int lrow = lane & 15;
  int lk4 = (lane >> 4) * 4;

  int an = nb + lrow;
  if (an >= n_nodes) an = n_nodes - 1;  // clamp; stores guarded later
  const float* hrow = h + (size_t)an * IN_DIM;

  f32x4 acc[4];
  #pragma unroll
  for (int nt = 0; nt < 4; ++nt) acc[nt] = (f32x4){0.f, 0.f, 0.f, 0.f};

  #pragma unroll
  for (int ks = 0; ks < 8; ++ks) {
    float4 hv = *(const float4*)(hrow + ks * 16 + lk4);
    half4 a;
    a[0] = (_Float16)hv.x; a[1] = (_Float16)hv.y;
    a[2] = (_Float16)hv.z; a[3] = (_Float16)hv.w;
    #pragma unroll
    for (int nt = 0; nt < 4; ++nt) {
      const float* wrow = W_fc + (size_t)(nt * 16 + lrow) * IN_DIM + ks * 16 + lk4;
      float4 wv = *(const float4*)wrow;
      half4 b;
      b[0] = (_Float16)wv.x; b[1] = (_Float16)wv.y;
      b[2] = (_Float16)wv.z; b[3] = (_Float16)wv.w;
      acc[nt] = __builtin_amdgcn_mfma_f32_16x16x16f16(a, b, acc[nt], 0, 0, 0);
    }
  }

  int drow = (lane >> 4) * 4;
  #pragma unroll
  for (int nt = 0; nt < 4; ++nt)
    #pragma unroll
    for (int r = 0; r < 4; ++r)
      zl[w][drow + r][nt * 16 + lrow] = acc[nt][r];

  int node = lane >> 2;    // 0..15
  int chunk = lane & 3;    // 0..3, 16 outs each
  float v[16];
  #pragma unroll
  for (int q = 0; q < 4; ++q) {
    float4 t = *(const float4*)&zl[w][node][chunk * 16 + q * 4];
    v[4 * q + 0] = t.x; v[4 * q + 1] = t.y;
    v[4 * q + 2] = t.z; v[4 * q + 3] = t.w;
  }

  int gn = nb + node;
  bool valid = gn < n_nodes;
  bool isword = gn < n_words;
  const float* wa = W_attn + (isword ? 0 : OUT_DIM) + chunk * 16;
  float p = 0.f;
  #pragma unroll
  for (int t = 0; t < 16; ++t) p = fmaf(v[t], wa[t], p);
  p += __shfl_xor(p, 1);
  p += __shfl_xor(p, 2);

  if (valid && chunk == 0) {
    if (isword) s1[gn] = p; else s2[gn - n_words] = p;
  }
  if (valid && isword) {
    uint32 d[8];
    #pragma unroll
    for (int k = 0; k < 8; ++k) {
      __half2 t = __floats2half2_rn(v[2 * k], v[2 * k + 1]);
      d[k] = *(uint32*)&t;
    }
    uint4* dstp = (uint4*)(z + (size_t)gn * OUT_DIM + chunk * 16);
    dstp[0] = make_uint4(d[0], d[1], d[2], d[3]);
    dstp[1] = make_uint4(d[4], d[5], d[6], d[7]);
  }
}

// K2: histogram of dst + per-edge rank (round-5 version, frozen)
__global__ __launch_bounds__(256) void k_hist(const int* __restrict__ dst,
                                              uint32* __restrict__ cnt,
                                              uint32* __restrict__ rank, int E) {
  int e = blockIdx.x * 256 + threadIdx.x;
  if (e < E) rank[e] = atomicAdd(&cnt[dst[e]], 1u);
}

// K3: exclusive scan of cnt[0..n) -> off[0..n] (frozen)
__global__ __launch_bounds__(1024) void k_scan(const uint32* __restrict__ cnt,
    uint32* __restrict__ off, int n) {
  __shared__ uint32 part[1024];
  int t = threadIdx.x;
  int CH = (n + 1023) >> 10;
  int base = t * CH;
  uint32 s = 0;
  for (int k = 0; k < CH; ++k) { int i = base + k; if (i < n) s += cnt[i]; }
  part[t] = s;
  __syncthreads();
  uint32 x = s;
  for (int d = 1; d < 1024; d <<= 1) {
    uint32 v = (t >= d) ? part[t - d] : 0u;
    __syncthreads();
    x += v;
    part[t] = x;
    __syncthreads();
  }
  uint32 run = (t > 0) ? part[t - 1] : 0u;
  for (int k = 0; k < CH; ++k) {
    int i = base + k;
    if (i < n) { off[i] = run; run += cnt[i]; }
  }
  if (t == 1023) off[n] = part[1023];
}

// K4: LDS-staged edge kernel. Block stages 256 tfidf rows (51.2 KB) via
// fully-coalesced float4 loads, then each thread dots its row from LDS.
// Row stride 51 floats -> at step k lanes hit banks (19t+k)%32, 2/bank = free.
__global__ __launch_bounds__(256) void k_edge(const float* __restrict__ tfidf,
    const int* __restrict__ src, const int* __restrict__ dst,
    const float* __restrict__ s1, const float* __restrict__ s2,
    const float* __restrict__ v3, const uint32* __restrict__ off,
    const uint32* __restrict__ rank, float2* __restrict__ pair, int E) {
  __shared__ float sd[256 * FPAD];
  int tid = threadIdx.x;
  int erow0 = blockIdx.x * 256;
  size_t base_f = (size_t)erow0 * FEATD;
  int nrows = E - erow0; if (nrows > 256) nrows = 256;
  int nf = nrows * FEATD;
  int n4 = nf >> 2;
  const float4* g4 = (const float4*)(tfidf + base_f);  // 51200B/block: 16B-aligned
  for (int i = tid; i < n4; i += 256) {
    float4 v = g4[i];
    int f0 = i << 2;
    #pragma unroll
    for (int j = 0; j < 4; ++j) {
      int f = f0 + j;
      int r = f / FEATD;           // const-div -> mul_hi
      int c = f - r * FEATD;
      sd[r * FPAD + c] = ((const float*)&v)[j];
    }
  }
  for (int f = (n4 << 2) + tid; f < nf; f += 256) {  // scalar tail (nf%4)
    int r = f / FEATD, c = f - r * FEATD;
    sd[r * FPAD + c] = tfidf[base_f + f];
  }
  __syncthreads();
  int e = erow0 + tid;
  if (e >= E) return;
  const float* row = sd + tid * FPAD;
  float f = 0.f;
  #pragma unroll
  for (int k = 0; k < FEATD; ++k) f = fmaf(row[k], v3[k], f);  // v3: uniform s_load
  int sidx = src[e], d = dst[e];
  float ev = s1[sidx] + s2[d] + f;
  ev = ev >= 0.f ? ev : NEG_SLOPE * ev;
  float2 pr;
  pr.x = __expf(ev);
  pr.y = __int_as_float(sidx);
  pair[off[d] + rank[e]] = pr;
}

// K5: one wave per sentence (4 per block), frozen round-5 version.
__global__ __launch_bounds__(256) void k_agg(const __half* __restrict__ z,
    const float2* __restrict__ pair, const uint32* __restrict__ off,
    float* __restrict__ out, int n_sents) {
  int w = threadIdx.x >> 6, lane = threadIdx.x & 63;
  int s = blockIdx.x * 4 + w;
  if (s >= n_sents) return;
  uint32 j0 = off[s], j1 = off[s + 1];

  float acc = 0.f, sa = 0.f;
  uint32 j = j0;
  for (; j + 8 <= j1; j += 8) {
    float2 p[8];
    #pragma unroll
    for (int k = 0; k < 8; ++k) p[k] = pair[j + k];
    float v[8];
    #pragma unroll
    for (int k = 0; k < 8; ++k)
      v[k] = __half2float(z[(size_t)(uint32)__float_as_int(p[k].y) * OUT_DIM + lane]);
    #pragma unroll
    for (int k = 0; k < 8; ++k) { acc = fmaf(p[k].x, v[k], acc); sa += p[k].x; }
  }
  for (; j + 4 <= j1; j += 4) {
    float2 p[4];
    #pragma unroll
    for (int k = 0; k < 4; ++k) p[k] = pair[j + k];
    float v[4];
    #pragma unroll
    for (int k = 0; k < 4; ++k)
      v[k] = __half2float(z[(size_t)(uint32)__float_as_int(p[k].y) * OUT_DIM + lane]);
    #pragma unroll
    for (int k = 0; k < 4; ++k) { acc = fmaf(p[k].x, v[k], acc); sa += p[k].x; }
  }
  for (; j < j1; ++j) {
    float2 p = pair[j];
    float v = __half2float(z[(size_t)(uint32)__float_as_int(p.y) * OUT_DIM + lane]);
    acc = fmaf(p.x, v, acc);
    sa += p.x;
  }

  out[(size_t)s * OUT_DIM + lane] = (sa > 0.f) ? (acc / sa) : 0.f;
}

extern "C" void kernel_launch(void* const* d_in, const int* in_sizes, int n_in,
                              void* d_out, int out_size, void* d_ws, size_t ws_size,
                              hipStream_t stream) {
  const float* h      = (const float*)d_in[0];
  const float* tfidf  = (const float*)d_in[1];
  const float* W_fc   = (const float*)d_in[2];
  const float* W_feat = (const float*)d_in[3];
  const float* W_attn = (const float*)d_in[4];
  const int*   src    = (const int*)d_in[5];
  const int*   dst    = (const int*)d_in[6];

  int n_nodes = in_sizes[0] / IN_DIM;   // 220000
  int E       = in_sizes[5];            // 2,000,000
  int n_sents = out_size / OUT_DIM;     // 20000
  int n_words = n_nodes - n_sents;      // 200000
  float* out = (float*)d_out;

  char* ws = (char*)d_ws;
  size_t ofs = 0;
  auto alloc = [&](size_t bytes) -> char* {
    char* p = ws + ofs;
    ofs += (bytes + 255) / 256 * 256;
    return p;
  };
  __half* z      = (__half*)alloc((size_t)n_words * OUT_DIM * 2);
  float*  s1     = (float*)alloc((size_t)n_words * 4);
  float*  s2     = (float*)alloc((size_t)n_sents * 4);
  float2* pair   = (float2*)alloc((size_t)E * 8);
  uint32* rank   = (uint32*)alloc((size_t)E * 4);
  uint32* cnt    = (uint32*)alloc((size_t)n_sents * 4);
  uint32* offs   = (uint32*)alloc((size_t)(n_sents + 1) * 4);
  float*  v3     = (float*)alloc(FEATD * 4);
  (void)ws_size; (void)n_in;

  k_v3zero<<<(n_sents + 255) / 256, 256, 0, stream>>>(W_feat, W_attn, v3, cnt,
                                                      n_sents);
  k_node_mfma<<<(n_nodes + 63) / 64, 256, 0, stream>>>(h, W_fc, W_attn, z, s1,
                                                       s2, n_words, n_nodes);
  k_hist<<<(E + 255) / 256, 256, 0, stream>>>(dst, cnt, rank, E);
  k_scan<<<1, 1024, 0, stream>>>(cnt, offs, n_sents);
  k_edge<<<(E + 255) / 256, 256, 0, stream>>>(tfidf, src, dst, s1, s2, v3,
                                              offs, rank, pair, E);
  k_agg<<<(n_sents + 3) / 4, 256, 0, stream>>>(z, pair, offs, out, n_sents);
}

// Round 9
// 382.447 us; speedup vs baseline: 1.2756x; 1.1258x over previous
//
#include <hip/hip_runtime.h>
#include <hip/hip_bf16.h>
#include <hip/hip_fp16.h>
#include <cstdint>

#define IN_DIM 128
#define OUT_DIM 64
#define FEATD 50
#define NEG_SLOPE 0.01f

typedef unsigned int uint32;
typedef _Float16 half4 __attribute__((ext_vector_type(4)));
typedef float f32x4 __attribute__((ext_vector_type(4)));

// K0: v3[j] = sum_o W_attn[128+o] * W_feat[o*FEATD+j]  (block 0) + zero cnt
__global__ __launch_bounds__(256) void k_v3zero(const float* __restrict__ W_feat,
                                                const float* __restrict__ W_attn,
                                                float* __restrict__ v3,
                                                uint32* __restrict__ cnt,
                                                int n_sents) {
  int i = blockIdx.x * 256 + threadIdx.x;
  if (i < n_sents) cnt[i] = 0u;
  if (blockIdx.x == 0 && threadIdx.x < FEATD) {
    int j = threadIdx.x;
    float s = 0.f;
    #pragma unroll
    for (int o = 0; o < OUT_DIM; ++o)
      s = fmaf(W_attn[2 * OUT_DIM + o], W_feat[o * FEATD + j], s);
    v3[j] = s;
  }
}

// K1: node GEMM on matrix cores (round-5 version, frozen).
__global__ __launch_bounds__(256) void k_node_mfma(const float* __restrict__ h,
    const float* __restrict__ W_fc, const float* __restrict__ W_attn,
    __half* __restrict__ z, float* __restrict__ s1, float* __restrict__ s2,
    int n_words, int n_nodes) {
  __shared__ float zl[4][16][68];  // +4 pad: conflict-free transpose
  int w = threadIdx.x >> 6, lane = threadIdx.x & 63;
  int nb = blockIdx.x * 64 + w * 16;
  int lrow = lane & 15;
  int lk4 = (lane >> 4) * 4;

  int an = nb + lrow;
  if (an >= n_nodes) an = n_nodes - 1;  // clamp; stores guarded later
  const float* hrow = h + (size_t)an * IN_DIM;

  f32x4 acc[4];
  #pragma unroll
  for (int nt = 0; nt < 4; ++nt) acc[nt] = (f32x4){0.f, 0.f, 0.f, 0.f};

  #pragma unroll
  for (int ks = 0; ks < 8; ++ks) {
    float4 hv = *(const float4*)(hrow + ks * 16 + lk4);
    half4 a;
    a[0] = (_Float16)hv.x; a[1] = (_Float16)hv.y;
    a[2] = (_Float16)hv.z; a[3] = (_Float16)hv.w;
    #pragma unroll
    for (int nt = 0; nt < 4; ++nt) {
      const float* wrow = W_fc + (size_t)(nt * 16 + lrow) * IN_DIM + ks * 16 + lk4;
      float4 wv = *(const float4*)wrow;
      half4 b;
      b[0] = (_Float16)wv.x; b[1] = (_Float16)wv.y;
      b[2] = (_Float16)wv.z; b[3] = (_Float16)wv.w;
      acc[nt] = __builtin_amdgcn_mfma_f32_16x16x16f16(a, b, acc[nt], 0, 0, 0);
    }
  }

  int drow = (lane >> 4) * 4;
  #pragma unroll
  for (int nt = 0; nt < 4; ++nt)
    #pragma unroll
    for (int r = 0; r < 4; ++r)
      zl[w][drow + r][nt * 16 + lrow] = acc[nt][r];

  int node = lane >> 2;    // 0..15
  int chunk = lane & 3;    // 0..3, 16 outs each
  float v[16];
  #pragma unroll
  for (int q = 0; q < 4; ++q) {
    float4 t = *(const float4*)&zl[w][node][chunk * 16 + q * 4];
    v[4 * q + 0] = t.x; v[4 * q + 1] = t.y;
    v[4 * q + 2] = t.z; v[4 * q + 3] = t.w;
  }

  int gn = nb + node;
  bool valid = gn < n_nodes;
  bool isword = gn < n_words;
  const float* wa = W_attn + (isword ? 0 : OUT_DIM) + chunk * 16;
  float p = 0.f;
  #pragma unroll
  for (int t = 0; t < 16; ++t) p = fmaf(v[t], wa[t], p);
  p += __shfl_xor(p, 1);
  p += __shfl_xor(p, 2);

  if (valid && chunk == 0) {
    if (isword) s1[gn] = p; else s2[gn - n_words] = p;
  }
  if (valid && isword) {
    uint32 d[8];
    #pragma unroll
    for (int k = 0; k < 8; ++k) {
      __half2 t = __floats2half2_rn(v[2 * k], v[2 * k + 1]);
      d[k] = *(uint32*)&t;
    }
    uint4* dstp = (uint4*)(z + (size_t)gn * OUT_DIM + chunk * 16);
    dstp[0] = make_uint4(d[0], d[1], d[2], d[3]);
    dstp[1] = make_uint4(d[4], d[5], d[6], d[7]);
  }
}

// K2: histogram of dst + per-edge rank (round-5 version, frozen)
__global__ __launch_bounds__(256) void k_hist(const int* __restrict__ dst,
                                              uint32* __restrict__ cnt,
                                              uint32* __restrict__ rank, int E) {
  int e = blockIdx.x * 256 + threadIdx.x;
  if (e < E) rank[e] = atomicAdd(&cnt[dst[e]], 1u);
}

// K3: exclusive scan of cnt[0..n) -> off[0..n] (frozen)
__global__ __launch_bounds__(1024) void k_scan(const uint32* __restrict__ cnt,
    uint32* __restrict__ off, int n) {
  __shared__ uint32 part[1024];
  int t = threadIdx.x;
  int CH = (n + 1023) >> 10;
  int base = t * CH;
  uint32 s = 0;
  for (int k = 0; k < CH; ++k) { int i = base + k; if (i < n) s += cnt[i]; }
  part[t] = s;
  __syncthreads();
  uint32 x = s;
  for (int d = 1; d < 1024; d <<= 1) {
    uint32 v = (t >= d) ? part[t - d] : 0u;
    __syncthreads();
    x += v;
    part[t] = x;
    __syncthreads();
  }
  uint32 run = (t > 0) ? part[t - 1] : 0u;
  for (int k = 0; k < CH; ++k) {
    int i = base + k;
    if (i < n) { off[i] = run; run += cnt[i]; }
  }
  if (t == 1023) off[n] = part[1023];
}

// K4: per edge (round-5 version, frozen): f = tfidf.v3 ; e = leaky(...);
//     store {exp(e), src} at off[dst]+rank (no atomics)
__global__ __launch_bounds__(256) void k_edge(const float* __restrict__ tfidf,
    const int* __restrict__ src, const int* __restrict__ dst,
    const float* __restrict__ s1, const float* __restrict__ s2,
    const float* __restrict__ v3, const uint32* __restrict__ off,
    const uint32* __restrict__ rank, float2* __restrict__ pair, int E) {
  int e = blockIdx.x * 256 + threadIdx.x;
  if (e >= E) return;
  const float* row = tfidf + (size_t)e * FEATD;
  float f = 0.f;
  #pragma unroll
  for (int k = 0; k < FEATD / 2; ++k) {
    float2 v = *(const float2*)(row + 2 * k);
    f = fmaf(v.x, v3[2 * k], f);
    f = fmaf(v.y, v3[2 * k + 1], f);
  }
  int sidx = src[e], d = dst[e];
  float ev = s1[sidx] + s2[d] + f;
  ev = ev >= 0.f ? ev : NEG_SLOPE * ev;
  float exv = __expf(ev);
  float2 pr;
  pr.x = exv;
  pr.y = __int_as_float(sidx);
  pair[off[d] + rank[e]] = pr;
}

// K5: one wave per sentence; 4 z-rows per gather instruction.
// Lane group g = lane>>4 handles edges j == g (mod 4); each lane loads 8 B
// (4 dims, uint2) of its group's row -> 512 B per wave-instruction, 4 KB in
// flight at unroll 8. Cross-group reduce via 2 shfl_xor; lanes 0-15 write a
// coalesced float4 row.
__global__ __launch_bounds__(256) void k_agg(const __half* __restrict__ z,
    const float2* __restrict__ pair, const uint32* __restrict__ off,
    float* __restrict__ out, int n_sents) {
  int w = threadIdx.x >> 6, lane = threadIdx.x & 63;
  int s = blockIdx.x * 4 + w;
  if (s >= n_sents) return;
  uint32 j0 = off[s], j1 = off[s + 1];
  int sub = lane >> 4;       // 0..3: edge sub-stream
  int d4 = (lane & 15) * 4;  // dim base

  float a0 = 0.f, a1 = 0.f, a2 = 0.f, a3 = 0.f, sa = 0.f;
  uint32 b = j0;
  for (; b + 32 <= j1; b += 32) {
    float2 p[8];
    #pragma unroll
    for (int k = 0; k < 8; ++k) p[k] = pair[b + 4 * k + sub];
    uint2 u[8];
    #pragma unroll
    for (int k = 0; k < 8; ++k) {
      uint32 sv = (uint32)__float_as_int(p[k].y);
      u[k] = *(const uint2*)(z + (size_t)sv * OUT_DIM + d4);
    }
    #pragma unroll
    for (int k = 0; k < 8; ++k) {
      float al = p[k].x;
      __half2 h01 = *(__half2*)&u[k].x;
      __half2 h23 = *(__half2*)&u[k].y;
      a0 = fmaf(al, __low2float(h01), a0);
      a1 = fmaf(al, __high2float(h01), a1);
      a2 = fmaf(al, __low2float(h23), a2);
      a3 = fmaf(al, __high2float(h23), a3);
      sa += al;
    }
  }
  for (; b + 4 <= j1; b += 4) {
    float2 p = pair[b + sub];
    uint32 sv = (uint32)__float_as_int(p.y);
    uint2 u = *(const uint2*)(z + (size_t)sv * OUT_DIM + d4);
    float al = p.x;
    __half2 h01 = *(__half2*)&u.x;
    __half2 h23 = *(__half2*)&u.y;
    a0 = fmaf(al, __low2float(h01), a0);
    a1 = fmaf(al, __high2float(h01), a1);
    a2 = fmaf(al, __low2float(h23), a2);
    a3 = fmaf(al, __high2float(h23), a3);
    sa += al;
  }
  if (sub < (int)(j1 - b)) {  // remainder 0..3 edges
    float2 p = pair[b + sub];
    uint32 sv = (uint32)__float_as_int(p.y);
    uint2 u = *(const uint2*)(z + (size_t)sv * OUT_DIM + d4);
    float al = p.x;
    __half2 h01 = *(__half2*)&u.x;
    __half2 h23 = *(__half2*)&u.y;
    a0 = fmaf(al, __low2float(h01), a0);
    a1 = fmaf(al, __high2float(h01), a1);
    a2 = fmaf(al, __low2float(h23), a2);
    a3 = fmaf(al, __high2float(h23), a3);
    sa += al;
  }

  // reduce across the 4 sub-streams (groups differ in lane bits 4-5)
  a0 += __shfl_xor(a0, 16); a0 += __shfl_xor(a0, 32);
  a1 += __shfl_xor(a1, 16); a1 += __shfl_xor(a1, 32);
  a2 += __shfl_xor(a2, 16); a2 += __shfl_xor(a2, 32);
  a3 += __shfl_xor(a3, 16); a3 += __shfl_xor(a3, 32);
  sa += __shfl_xor(sa, 16); sa += __shfl_xor(sa, 32);

  if (sub == 0) {
    float inv = (sa > 0.f) ? (1.f / sa) : 0.f;
    float4 o;
    o.x = a0 * inv; o.y = a1 * inv; o.z = a2 * inv; o.w = a3 * inv;
    *(float4*)(out + (size_t)s * OUT_DIM + d4) = o;
  }
}

extern "C" void kernel_launch(void* const* d_in, const int* in_sizes, int n_in,
                              void* d_out, int out_size, void* d_ws, size_t ws_size,
                              hipStream_t stream) {
  const float* h      = (const float*)d_in[0];
  const float* tfidf  = (const float*)d_in[1];
  const float* W_fc   = (const float*)d_in[2];
  const float* W_feat = (const float*)d_in[3];
  const float* W_attn = (const float*)d_in[4];
  const int*   src    = (const int*)d_in[5];
  const int*   dst    = (const int*)d_in[6];

  int n_nodes = in_sizes[0] / IN_DIM;   // 220000
  int E       = in_sizes[5];            // 2,000,000
  int n_sents = out_size / OUT_DIM;     // 20000
  int n_words = n_nodes - n_sents;      // 200000
  float* out = (float*)d_out;

  char* ws = (char*)d_ws;
  size_t ofs = 0;
  auto alloc = [&](size_t bytes) -> char* {
    char* p = ws + ofs;
    ofs += (bytes + 255) / 256 * 256;
    return p;
  };
  __half* z      = (__half*)alloc((size_t)n_words * OUT_DIM * 2);
  float*  s1     = (float*)alloc((size_t)n_words * 4);
  float*  s2     = (float*)alloc((size_t)n_sents * 4);
  float2* pair   = (float2*)alloc((size_t)E * 8);
  uint32* rank   = (uint32*)alloc((size_t)E * 4);
  uint32* cnt    = (uint32*)alloc((size_t)n_sents * 4);
  uint32* offs   = (uint32*)alloc((size_t)(n_sents + 1) * 4);
  float*  v3     = (float*)alloc(FEATD * 4);
  (void)ws_size; (void)n_in;

  k_v3zero<<<(n_sents + 255) / 256, 256, 0, stream>>>(W_feat, W_attn, v3, cnt,
                                                      n_sents);
  k_node_mfma<<<(n_nodes + 63) / 64, 256, 0, stream>>>(h, W_fc, W_attn, z, s1,
                                                       s2, n_words, n_nodes);
  k_hist<<<(E + 255) / 256, 256, 0, stream>>>(dst, cnt, rank, E);
  k_scan<<<1, 1024, 0, stream>>>(cnt, offs, n_sents);
  k_edge<<<(E + 255) / 256, 256, 0, stream>>>(tfidf, src, dst, s1, s2, v3,
                                              offs, rank, pair, E);
  k_agg<<<(n_sents + 3) / 4, 256, 0, stream>>>(z, pair, offs, out, n_sents);
}